// Round 1
// baseline (475.423 us; speedup 1.0000x reference)
//
#include <hip/hip_runtime.h>
#include <math.h>

#define N_NODES 100000
#define DIM 64
#define N_EDGES 1600000
#define SCAN_CHUNK 1024
#define N_CHUNKS ((N_NODES + SCAN_CHUNK - 1) / SCAN_CHUNK)  // 98

// ---------------------------------------------------------------------------
// K1: per-node linears. M = x@Wm + bm ; out = x@Wr + br ; s = mean(M) (BETA=1)
// One wave per node, grid-stride. Weights live in registers (lane j holds
// column j for all 64 k). x row broadcast via __shfl.
// ---------------------------------------------------------------------------
__global__ __launch_bounds__(256) void k_linear(
        const float* __restrict__ x,
        const float* __restrict__ Wm, const float* __restrict__ bm,
        const float* __restrict__ Wr, const float* __restrict__ br,
        float* __restrict__ M, float* __restrict__ s, float* __restrict__ out) {
    const int lane = threadIdx.x & 63;
    const int wave = (blockIdx.x * blockDim.x + threadIdx.x) >> 6;
    const int nwaves = (gridDim.x * blockDim.x) >> 6;

    float wm[DIM], wr[DIM];
#pragma unroll
    for (int k = 0; k < DIM; ++k) {
        wm[k] = Wm[k * DIM + lane];
        wr[k] = Wr[k * DIM + lane];
    }
    const float bmv = bm[lane];
    const float brv = br[lane];

    for (int i = wave; i < N_NODES; i += nwaves) {
        const float xv = x[i * DIM + lane];
        float am = bmv, ar = brv;
#pragma unroll
        for (int k = 0; k < DIM; ++k) {
            const float xk = __shfl(xv, k, 64);
            am = fmaf(xk, wm[k], am);
            ar = fmaf(xk, wr[k], ar);
        }
        M[i * DIM + lane] = am;
        out[i * DIM + lane] = ar;
        // row sum across 64 lanes -> s[i]
        float t = am;
#pragma unroll
        for (int o = 32; o > 0; o >>= 1) t += __shfl_xor(t, o, 64);
        if (lane == 0) s[i] = t * (1.0f / DIM);
    }
}

// ---------------------------------------------------------------------------
// CSR build by destination
// ---------------------------------------------------------------------------
__global__ void k_count(const int* __restrict__ col, int* __restrict__ counts) {
    int e = blockIdx.x * blockDim.x + threadIdx.x;
    const int stride = gridDim.x * blockDim.x;
    for (; e < N_EDGES; e += stride) atomicAdd(&counts[col[e]], 1);
}

__global__ __launch_bounds__(SCAN_CHUNK) void k_scan1(
        const int* __restrict__ counts, int* __restrict__ offs,
        int* __restrict__ chunk_sums) {
    __shared__ int sd[SCAN_CHUNK];
    const int t = threadIdx.x;
    const int idx = blockIdx.x * SCAN_CHUNK + t;
    const int v = (idx < N_NODES) ? counts[idx] : 0;
    sd[t] = v;
    __syncthreads();
    for (int o = 1; o < SCAN_CHUNK; o <<= 1) {
        const int add = (t >= o) ? sd[t - o] : 0;
        __syncthreads();
        sd[t] += add;
        __syncthreads();
    }
    if (idx < N_NODES) offs[idx] = sd[t] - v;  // exclusive scan
    if (t == SCAN_CHUNK - 1) chunk_sums[blockIdx.x] = sd[t];
}

__global__ __launch_bounds__(128) void k_scan2(int* __restrict__ chunk_sums) {
    __shared__ int sd[128];
    const int t = threadIdx.x;
    const int v = (t < N_CHUNKS) ? chunk_sums[t] : 0;
    sd[t] = v;
    __syncthreads();
    for (int o = 1; o < 128; o <<= 1) {
        const int add = (t >= o) ? sd[t - o] : 0;
        __syncthreads();
        sd[t] += add;
        __syncthreads();
    }
    if (t < N_CHUNKS) chunk_sums[t] = sd[t] - v;  // exclusive over chunk sums
}

__global__ __launch_bounds__(SCAN_CHUNK) void k_scan3(
        int* __restrict__ offs, const int* __restrict__ chunk_sums) {
    const int idx = blockIdx.x * SCAN_CHUNK + threadIdx.x;
    if (idx < N_NODES) offs[idx] += chunk_sums[blockIdx.x];
    if (idx == 0) offs[N_NODES] = N_EDGES;
}

__global__ void k_fill(const int* __restrict__ row, const int* __restrict__ col,
                       const int* __restrict__ offs, int* __restrict__ cursor,
                       int* __restrict__ csr_src) {
    int e = blockIdx.x * blockDim.x + threadIdx.x;
    const int stride = gridDim.x * blockDim.x;
    for (; e < N_EDGES; e += stride) {
        const int c = col[e];
        const int slot = offs[c] + atomicAdd(&cursor[c], 1);
        csr_src[slot] = row[e];
    }
}

// ---------------------------------------------------------------------------
// K5: per-destination softmax + weighted aggregation. One wave per node.
// out[n][j] += sum_e softmax(s[src_e]) * M[src_e][j]
// ---------------------------------------------------------------------------
__global__ __launch_bounds__(256) void k_gather(
        const int* __restrict__ offs, const int* __restrict__ csr_src,
        const float* __restrict__ s, const float* __restrict__ M,
        float* __restrict__ out) {
    const int lane = threadIdx.x & 63;
    const int n = (blockIdx.x * blockDim.x + threadIdx.x) >> 6;
    if (n >= N_NODES) return;
    const int beg = offs[n], end = offs[n + 1];
    if (beg == end) return;  // no incoming edges: out stays x@Wr + br

    // pass A: lane-parallel max of s over incoming edges
    float mloc = -INFINITY;
    for (int base = beg; base < end; base += 64) {
        const int idx = base + lane;
        if (idx < end) mloc = fmaxf(mloc, s[csr_src[idx]]);
    }
#pragma unroll
    for (int o = 32; o > 0; o >>= 1) mloc = fmaxf(mloc, __shfl_xor(mloc, o, 64));

    // pass B: online weighted accumulation
    float l = 0.f, acc = 0.f;
    for (int base = beg; base < end; base += 64) {
        const int idx = base + lane;
        const int src_l = (idx < end) ? csr_src[idx] : 0;
        const float sv_l = (idx < end) ? s[src_l] : 0.f;
        const int cnt = min(64, end - base);
        for (int k = 0; k < cnt; ++k) {
            const int src = __shfl(src_l, k, 64);
            const float w = __expf(__shfl(sv_l, k, 64) - mloc);
            l += w;
            acc = fmaf(w, M[src * DIM + lane], acc);
        }
    }
    out[n * DIM + lane] += acc / l;
}

// ---------------------------------------------------------------------------
extern "C" void kernel_launch(void* const* d_in, const int* in_sizes, int n_in,
                              void* d_out, int out_size, void* d_ws, size_t ws_size,
                              hipStream_t stream) {
    const float* x  = (const float*)d_in[0];
    const int*   ei = (const int*)d_in[1];
    const float* Wm = (const float*)d_in[2];
    const float* bm = (const float*)d_in[3];
    const float* Wr = (const float*)d_in[4];
    const float* br = (const float*)d_in[5];
    float* out = (float*)d_out;
    const int* row = ei;            // edge_index[0]
    const int* col = ei + N_EDGES;  // edge_index[1]

    char* ws = (char*)d_ws;
    float* M      = (float*)ws;  ws += (size_t)N_NODES * DIM * sizeof(float);
    float* s      = (float*)ws;  ws += (size_t)N_NODES * sizeof(float);
    int* counts   = (int*)ws;    ws += (size_t)N_NODES * sizeof(int);
    int* offs     = (int*)ws;    ws += (size_t)(N_NODES + 1) * sizeof(int);
    int* cursor   = (int*)ws;    ws += (size_t)N_NODES * sizeof(int);
    int* chunks   = (int*)ws;    ws += (size_t)1024 * sizeof(int);
    int* csr_src  = (int*)ws;    ws += (size_t)N_EDGES * sizeof(int);

    hipMemsetAsync(counts, 0, N_NODES * sizeof(int), stream);
    hipMemsetAsync(cursor, 0, N_NODES * sizeof(int), stream);

    k_linear<<<1024, 256, 0, stream>>>(x, Wm, bm, Wr, br, M, s, out);
    k_count<<<2048, 256, 0, stream>>>(col, counts);
    k_scan1<<<N_CHUNKS, SCAN_CHUNK, 0, stream>>>(counts, offs, chunks);
    k_scan2<<<1, 128, 0, stream>>>(chunks);
    k_scan3<<<N_CHUNKS, SCAN_CHUNK, 0, stream>>>(offs, chunks);
    k_fill<<<2048, 256, 0, stream>>>(row, col, offs, cursor, csr_src);
    k_gather<<<(N_NODES + 3) / 4, 256, 0, stream>>>(offs, csr_src, s, M, out);
}

// Round 2
// 340.041 us; speedup vs baseline: 1.3981x; 1.3981x over previous
//
#include <hip/hip_runtime.h>
#include <math.h>

#define N_NODES 100000
#define DIM 64
#define N_EDGES 1600000
#define SCAN_CHUNK 1024
#define N_CHUNKS ((N_NODES + SCAN_CHUNK - 1) / SCAN_CHUNK)  // 98

// ---------------------------------------------------------------------------
// K1: per-node linears. M = x@Wm + bm ; out = x@Wr + br ; es = exp(mean(M))
// One wave per node, grid-stride. Weights register-resident (lane j = col j).
// ---------------------------------------------------------------------------
__global__ __launch_bounds__(256) void k_linear(
        const float* __restrict__ x,
        const float* __restrict__ Wm, const float* __restrict__ bm,
        const float* __restrict__ Wr, const float* __restrict__ br,
        float* __restrict__ M, float* __restrict__ es, float* __restrict__ out) {
    const int lane = threadIdx.x & 63;
    const int wave = (blockIdx.x * blockDim.x + threadIdx.x) >> 6;
    const int nwaves = (gridDim.x * blockDim.x) >> 6;

    float wm[DIM], wr[DIM];
#pragma unroll
    for (int k = 0; k < DIM; ++k) {
        wm[k] = Wm[k * DIM + lane];
        wr[k] = Wr[k * DIM + lane];
    }
    const float bmv = bm[lane];
    const float brv = br[lane];

    for (int i = wave; i < N_NODES; i += nwaves) {
        const float xv = x[i * DIM + lane];
        float am = bmv, ar = brv;
#pragma unroll
        for (int k = 0; k < DIM; ++k) {
            const float xk = __shfl(xv, k, 64);
            am = fmaf(xk, wm[k], am);
            ar = fmaf(xk, wr[k], ar);
        }
        M[i * DIM + lane] = am;
        out[i * DIM + lane] = ar;
        float t = am;
#pragma unroll
        for (int o = 32; o > 0; o >>= 1) t += __shfl_xor(t, o, 64);
        if (lane == 0) es[i] = __expf(t * (1.0f / DIM));  // softmax shift-invariant: no max needed
    }
}

// ---------------------------------------------------------------------------
// CSR build by destination: one atomic pass assigns both count and rank.
// ---------------------------------------------------------------------------
__global__ void k_count_rank(const int* __restrict__ col, int* __restrict__ counts,
                             int* __restrict__ rank) {
    int e = blockIdx.x * blockDim.x + threadIdx.x;
    const int stride = gridDim.x * blockDim.x;
    for (; e < N_EDGES; e += stride) {
        rank[e] = atomicAdd(&counts[col[e]], 1);
    }
}

__global__ __launch_bounds__(SCAN_CHUNK) void k_scan1(
        const int* __restrict__ counts, int* __restrict__ offs,
        int* __restrict__ chunk_sums) {
    __shared__ int sd[SCAN_CHUNK];
    const int t = threadIdx.x;
    const int idx = blockIdx.x * SCAN_CHUNK + t;
    const int v = (idx < N_NODES) ? counts[idx] : 0;
    sd[t] = v;
    __syncthreads();
    for (int o = 1; o < SCAN_CHUNK; o <<= 1) {
        const int add = (t >= o) ? sd[t - o] : 0;
        __syncthreads();
        sd[t] += add;
        __syncthreads();
    }
    if (idx < N_NODES) offs[idx] = sd[t] - v;  // exclusive
    if (t == SCAN_CHUNK - 1) chunk_sums[blockIdx.x] = sd[t];
}

__global__ __launch_bounds__(128) void k_scan2(int* __restrict__ chunk_sums) {
    __shared__ int sd[128];
    const int t = threadIdx.x;
    const int v = (t < N_CHUNKS) ? chunk_sums[t] : 0;
    sd[t] = v;
    __syncthreads();
    for (int o = 1; o < 128; o <<= 1) {
        const int add = (t >= o) ? sd[t - o] : 0;
        __syncthreads();
        sd[t] += add;
        __syncthreads();
    }
    if (t < N_CHUNKS) chunk_sums[t] = sd[t] - v;
}

__global__ __launch_bounds__(SCAN_CHUNK) void k_scan3(
        int* __restrict__ offs, const int* __restrict__ chunk_sums) {
    const int idx = blockIdx.x * SCAN_CHUNK + threadIdx.x;
    if (idx < N_NODES) offs[idx] += chunk_sums[blockIdx.x];
    if (idx == 0) offs[N_NODES] = N_EDGES;
}

// Atomic-free fill: slot = offs[col] + rank.
__global__ void k_fill(const int* __restrict__ row, const int* __restrict__ col,
                       const int* __restrict__ rank, const int* __restrict__ offs,
                       int* __restrict__ csr_src) {
    int e = blockIdx.x * blockDim.x + threadIdx.x;
    const int stride = gridDim.x * blockDim.x;
    for (; e < N_EDGES; e += stride) {
        csr_src[offs[col[e]] + rank[e]] = row[e];
    }
}

// ---------------------------------------------------------------------------
// K5: per-destination aggregation. One wave per node; 4 groups of 16 lanes,
// each group processes a different edge per iteration; float4 M loads.
// out[n] += (sum_e es[src] * M[src]) / (sum_e es[src])
// ---------------------------------------------------------------------------
__global__ __launch_bounds__(256) void k_gather(
        const int* __restrict__ offs, const int* __restrict__ csr_src,
        const float* __restrict__ es, const float4* __restrict__ M4,
        float4* __restrict__ out4) {
    const int lane = threadIdx.x & 63;
    const int gl = lane & 15;   // lane within group
    const int g  = lane >> 4;   // group 0..3
    const int n = (blockIdx.x * blockDim.x + threadIdx.x) >> 6;
    if (n >= N_NODES) return;
    const int beg = offs[n], end = offs[n + 1];
    if (beg == end) return;  // out stays x@Wr + br

    float ax = 0.f, ay = 0.f, az = 0.f, aw = 0.f;
    float l = 0.f;
    for (int i = beg + g; i < end; i += 4) {
        const int src = csr_src[i];       // 16 lanes share addr -> 1 req/group
        const float w = es[src];
        const float4 m = M4[src * 16 + gl];
        l += w;
        ax = fmaf(w, m.x, ax);
        ay = fmaf(w, m.y, ay);
        az = fmaf(w, m.z, az);
        aw = fmaf(w, m.w, aw);
    }
    // combine the 4 groups (butterfly over group bits 16 and 32)
#pragma unroll
    for (int o = 16; o <= 32; o <<= 1) {
        ax += __shfl_xor(ax, o, 64);
        ay += __shfl_xor(ay, o, 64);
        az += __shfl_xor(az, o, 64);
        aw += __shfl_xor(aw, o, 64);
        l  += __shfl_xor(l,  o, 64);
    }
    if (g == 0) {
        const float inv = 1.0f / l;
        float4 r = out4[n * 16 + gl];
        r.x = fmaf(ax, inv, r.x);
        r.y = fmaf(ay, inv, r.y);
        r.z = fmaf(az, inv, r.z);
        r.w = fmaf(aw, inv, r.w);
        out4[n * 16 + gl] = r;
    }
}

// ---------------------------------------------------------------------------
extern "C" void kernel_launch(void* const* d_in, const int* in_sizes, int n_in,
                              void* d_out, int out_size, void* d_ws, size_t ws_size,
                              hipStream_t stream) {
    const float* x  = (const float*)d_in[0];
    const int*   ei = (const int*)d_in[1];
    const float* Wm = (const float*)d_in[2];
    const float* bm = (const float*)d_in[3];
    const float* Wr = (const float*)d_in[4];
    const float* br = (const float*)d_in[5];
    float* out = (float*)d_out;
    const int* row = ei;            // edge_index[0]
    const int* col = ei + N_EDGES;  // edge_index[1]

    char* ws = (char*)d_ws;
    float* M      = (float*)ws;  ws += (size_t)N_NODES * DIM * sizeof(float);
    float* es     = (float*)ws;  ws += (size_t)N_NODES * sizeof(float);
    int* counts   = (int*)ws;    ws += (size_t)N_NODES * sizeof(int);
    int* offs     = (int*)ws;    ws += (size_t)(N_NODES + 1) * sizeof(int);
    int* rank     = (int*)ws;    ws += (size_t)N_EDGES * sizeof(int);
    int* chunks   = (int*)ws;    ws += (size_t)1024 * sizeof(int);
    int* csr_src  = (int*)ws;    ws += (size_t)N_EDGES * sizeof(int);

    hipMemsetAsync(counts, 0, N_NODES * sizeof(int), stream);

    k_linear<<<1024, 256, 0, stream>>>(x, Wm, bm, Wr, br, M, es, out);
    k_count_rank<<<2048, 256, 0, stream>>>(col, counts, rank);
    k_scan1<<<N_CHUNKS, SCAN_CHUNK, 0, stream>>>(counts, offs, chunks);
    k_scan2<<<1, 128, 0, stream>>>(chunks);
    k_scan3<<<N_CHUNKS, SCAN_CHUNK, 0, stream>>>(offs, chunks);
    k_fill<<<2048, 256, 0, stream>>>(row, col, rank, offs, csr_src);
    k_gather<<<(N_NODES + 3) / 4, 256, 0, stream>>>(offs, csr_src, es,
                                                    (const float4*)M, (float4*)out);
}

// Round 3
// 282.306 us; speedup vs baseline: 1.6841x; 1.2045x over previous
//
#include <hip/hip_runtime.h>
#include <math.h>

#define N_NODES 100000
#define DIM 64
#define N_EDGES 1600000
#define SCAN_CHUNK 1024
#define N_CHUNKS ((N_NODES + SCAN_CHUNK - 1) / SCAN_CHUNK)  // 98

#define CNT_BLOCKS 2048
#define LIN_BLOCKS 1563  // ceil(6250 waves / 4 waves per block); 16 rows/wave
#define P1_BLOCKS (CNT_BLOCKS + LIN_BLOCKS)

typedef _Float16 half8 __attribute__((ext_vector_type(8)));
typedef float f32x4 __attribute__((ext_vector_type(4)));

// ---------------------------------------------------------------------------
// Phase 1 (fused, block-specialized):
//   blocks [0, CNT_BLOCKS): rank[e] = atomicAdd(&counts[col[e]], 1)
//   blocks [CNT_BLOCKS, ..): MFMA f16 GEMM  [16 x 64] @ [64 x 128] per wave
//     C cols 0..63  -> M = x@Wm + bm   (also es = exp(mean_row(M)))
//     C cols 64..127-> out = x@Wr + br
// MFMA f16 16x16x32 layouts (verified, §3):
//   A[m][k]: m = lane&15, k = (lane>>4)*8 + j
//   B[k][n]: n = lane&15, k = (lane>>4)*8 + j
//   C[r][c]: c = lane&15, r = (lane>>4)*4 + reg
// ---------------------------------------------------------------------------
__global__ __launch_bounds__(256) void k_phase1(
        const float* __restrict__ x,
        const float* __restrict__ Wm, const float* __restrict__ bm,
        const float* __restrict__ Wr, const float* __restrict__ br,
        const int* __restrict__ col, int* __restrict__ counts,
        int* __restrict__ rank,
        float* __restrict__ M, float* __restrict__ es, float* __restrict__ out) {
    if (blockIdx.x < CNT_BLOCKS) {
        int e = blockIdx.x * 256 + threadIdx.x;
        for (; e < N_EDGES; e += CNT_BLOCKS * 256) {
            rank[e] = atomicAdd(&counts[col[e]], 1);
        }
        return;
    }

    const int wave = (blockIdx.x - CNT_BLOCKS) * 4 + (threadIdx.x >> 6);
    if (wave >= N_NODES / 16) return;  // 6250 waves, 16 rows each
    const int lane = threadIdx.x & 63;
    const int quad = lane >> 4;
    const int l15 = lane & 15;
    const int row0 = wave * 16;

    // B fragments: 8 col-tiles (0-3 = Wm, 4-7 = Wr) x 2 k-chunks.
    half8 bfrag[8][2];
#pragma unroll
    for (int ct = 0; ct < 8; ++ct) {
        const float* W = (ct < 4) ? Wm : Wr;
        const int c = (ct & 3) * 16 + l15;
#pragma unroll
        for (int kc = 0; kc < 2; ++kc) {
            half8 f;
#pragma unroll
            for (int j = 0; j < 8; ++j)
                f[j] = (_Float16)W[(kc * 32 + quad * 8 + j) * DIM + c];
            bfrag[ct][kc] = f;
        }
    }

    // A fragments: row = row0 + l15, k = kc*32 + quad*8 + j
    half8 afrag[2];
#pragma unroll
    for (int kc = 0; kc < 2; ++kc) {
        const float* xp = x + (size_t)(row0 + l15) * DIM + kc * 32 + quad * 8;
        const float4 x0 = *(const float4*)xp;
        const float4 x1 = *(const float4*)(xp + 4);
        half8 f;
        f[0] = (_Float16)x0.x; f[1] = (_Float16)x0.y;
        f[2] = (_Float16)x0.z; f[3] = (_Float16)x0.w;
        f[4] = (_Float16)x1.x; f[5] = (_Float16)x1.y;
        f[6] = (_Float16)x1.z; f[7] = (_Float16)x1.w;
        afrag[kc] = f;
    }

    f32x4 acc[8];
#pragma unroll
    for (int ct = 0; ct < 8; ++ct) {
        f32x4 a = {0.f, 0.f, 0.f, 0.f};
        a = __builtin_amdgcn_mfma_f32_16x16x32_f16(afrag[0], bfrag[ct][0], a, 0, 0, 0);
        a = __builtin_amdgcn_mfma_f32_16x16x32_f16(afrag[1], bfrag[ct][1], a, 0, 0, 0);
        acc[ct] = a;
    }

    // Epilogue: bias add, stores, row sums for es.
    float rsum[4] = {0.f, 0.f, 0.f, 0.f};
#pragma unroll
    for (int ct = 0; ct < 8; ++ct) {
        const float bias = (ct < 4) ? bm[(ct & 3) * 16 + l15]
                                    : br[(ct & 3) * 16 + l15];
        float* dst = (ct < 4) ? M : out;
#pragma unroll
        for (int r = 0; r < 4; ++r) {
            const float v = acc[ct][r] + bias;
            dst[(size_t)(row0 + quad * 4 + r) * DIM + (ct & 3) * 16 + l15] = v;
            if (ct < 4) rsum[r] += v;
        }
    }
#pragma unroll
    for (int o = 1; o <= 8; o <<= 1) {
#pragma unroll
        for (int r = 0; r < 4; ++r) rsum[r] += __shfl_xor(rsum[r], o, 64);
    }
    if (l15 == 0) {
#pragma unroll
        for (int r = 0; r < 4; ++r)
            es[row0 + quad * 4 + r] = __expf(rsum[r] * (1.0f / DIM));
    }
}

// ---------------------------------------------------------------------------
// Scans over per-node counts -> CSR offsets
// ---------------------------------------------------------------------------
__global__ __launch_bounds__(SCAN_CHUNK) void k_scan1(
        const int* __restrict__ counts, int* __restrict__ offs,
        int* __restrict__ chunk_sums) {
    __shared__ int sd[SCAN_CHUNK];
    const int t = threadIdx.x;
    const int idx = blockIdx.x * SCAN_CHUNK + t;
    const int v = (idx < N_NODES) ? counts[idx] : 0;
    sd[t] = v;
    __syncthreads();
    for (int o = 1; o < SCAN_CHUNK; o <<= 1) {
        const int add = (t >= o) ? sd[t - o] : 0;
        __syncthreads();
        sd[t] += add;
        __syncthreads();
    }
    if (idx < N_NODES) offs[idx] = sd[t] - v;
    if (t == SCAN_CHUNK - 1) chunk_sums[blockIdx.x] = sd[t];
}

__global__ __launch_bounds__(128) void k_scan2(int* __restrict__ chunk_sums) {
    __shared__ int sd[128];
    const int t = threadIdx.x;
    const int v = (t < N_CHUNKS) ? chunk_sums[t] : 0;
    sd[t] = v;
    __syncthreads();
    for (int o = 1; o < 128; o <<= 1) {
        const int add = (t >= o) ? sd[t - o] : 0;
        __syncthreads();
        sd[t] += add;
        __syncthreads();
    }
    if (t < N_CHUNKS) chunk_sums[t] = sd[t] - v;
}

__global__ __launch_bounds__(SCAN_CHUNK) void k_scan3(
        int* __restrict__ offs, const int* __restrict__ chunk_sums) {
    const int idx = blockIdx.x * SCAN_CHUNK + threadIdx.x;
    if (idx < N_NODES) offs[idx] += chunk_sums[blockIdx.x];
    if (idx == 0) offs[N_NODES] = N_EDGES;
}

// Atomic-free fill: slot = offs[col] + rank.
__global__ void k_fill(const int* __restrict__ row, const int* __restrict__ col,
                       const int* __restrict__ rank, const int* __restrict__ offs,
                       int* __restrict__ csr_src) {
    int e = blockIdx.x * blockDim.x + threadIdx.x;
    const int stride = gridDim.x * blockDim.x;
    for (; e < N_EDGES; e += stride) {
        csr_src[offs[col[e]] + rank[e]] = row[e];
    }
}

// ---------------------------------------------------------------------------
// Gather: one wave per node; 4 groups of 16 lanes; 2 independent edge chains
// per group (8 outstanding gathers per wave). float4 M loads.
// ---------------------------------------------------------------------------
__global__ __launch_bounds__(256) void k_gather(
        const int* __restrict__ offs, const int* __restrict__ csr_src,
        const float* __restrict__ es, const float4* __restrict__ M4,
        float4* __restrict__ out4) {
    const int lane = threadIdx.x & 63;
    const int gl = lane & 15;
    const int g  = lane >> 4;
    const int n = (blockIdx.x * blockDim.x + threadIdx.x) >> 6;
    if (n >= N_NODES) return;
    const int beg = offs[n], end = offs[n + 1];
    if (beg == end) return;  // out stays x@Wr + br

    float a0x = 0.f, a0y = 0.f, a0z = 0.f, a0w = 0.f, l0 = 0.f;
    float a1x = 0.f, a1y = 0.f, a1z = 0.f, a1w = 0.f, l1 = 0.f;
    int i = beg + g;
    for (; i + 4 < end; i += 8) {
        const int s0 = csr_src[i];
        const int s1 = csr_src[i + 4];
        const float w0 = es[s0];
        const float w1 = es[s1];
        const float4 m0 = M4[(size_t)s0 * 16 + gl];
        const float4 m1 = M4[(size_t)s1 * 16 + gl];
        l0 += w0; l1 += w1;
        a0x = fmaf(w0, m0.x, a0x); a0y = fmaf(w0, m0.y, a0y);
        a0z = fmaf(w0, m0.z, a0z); a0w = fmaf(w0, m0.w, a0w);
        a1x = fmaf(w1, m1.x, a1x); a1y = fmaf(w1, m1.y, a1y);
        a1z = fmaf(w1, m1.z, a1z); a1w = fmaf(w1, m1.w, a1w);
    }
    if (i < end) {
        const int s0 = csr_src[i];
        const float w0 = es[s0];
        const float4 m0 = M4[(size_t)s0 * 16 + gl];
        l0 += w0;
        a0x = fmaf(w0, m0.x, a0x); a0y = fmaf(w0, m0.y, a0y);
        a0z = fmaf(w0, m0.z, a0z); a0w = fmaf(w0, m0.w, a0w);
    }
    float ax = a0x + a1x, ay = a0y + a1y, az = a0z + a1z, aw = a0w + a1w;
    float l = l0 + l1;
#pragma unroll
    for (int o = 16; o <= 32; o <<= 1) {
        ax += __shfl_xor(ax, o, 64);
        ay += __shfl_xor(ay, o, 64);
        az += __shfl_xor(az, o, 64);
        aw += __shfl_xor(aw, o, 64);
        l  += __shfl_xor(l,  o, 64);
    }
    if (g == 0) {
        const float inv = 1.0f / l;
        float4 r = out4[(size_t)n * 16 + gl];
        r.x = fmaf(ax, inv, r.x);
        r.y = fmaf(ay, inv, r.y);
        r.z = fmaf(az, inv, r.z);
        r.w = fmaf(aw, inv, r.w);
        out4[(size_t)n * 16 + gl] = r;
    }
}

// ---------------------------------------------------------------------------
extern "C" void kernel_launch(void* const* d_in, const int* in_sizes, int n_in,
                              void* d_out, int out_size, void* d_ws, size_t ws_size,
                              hipStream_t stream) {
    const float* x  = (const float*)d_in[0];
    const int*   ei = (const int*)d_in[1];
    const float* Wm = (const float*)d_in[2];
    const float* bm = (const float*)d_in[3];
    const float* Wr = (const float*)d_in[4];
    const float* br = (const float*)d_in[5];
    float* out = (float*)d_out;
    const int* row = ei;            // edge_index[0]
    const int* col = ei + N_EDGES;  // edge_index[1]

    char* ws = (char*)d_ws;
    float* M      = (float*)ws;  ws += (size_t)N_NODES * DIM * sizeof(float);
    float* es     = (float*)ws;  ws += (size_t)N_NODES * sizeof(float);
    int* counts   = (int*)ws;    ws += (size_t)N_NODES * sizeof(int);
    int* offs     = (int*)ws;    ws += (size_t)(N_NODES + 1) * sizeof(int);
    int* rank     = (int*)ws;    ws += (size_t)N_EDGES * sizeof(int);
    int* chunks   = (int*)ws;    ws += (size_t)1024 * sizeof(int);
    int* csr_src  = (int*)ws;    ws += (size_t)N_EDGES * sizeof(int);

    hipMemsetAsync(counts, 0, N_NODES * sizeof(int), stream);

    k_phase1<<<P1_BLOCKS, 256, 0, stream>>>(x, Wm, bm, Wr, br,
                                            col, counts, rank, M, es, out);
    k_scan1<<<N_CHUNKS, SCAN_CHUNK, 0, stream>>>(counts, offs, chunks);
    k_scan2<<<1, 128, 0, stream>>>(chunks);
    k_scan3<<<N_CHUNKS, SCAN_CHUNK, 0, stream>>>(offs, chunks);
    k_fill<<<2048, 256, 0, stream>>>(row, col, rank, offs, csr_src);
    k_gather<<<(N_NODES + 3) / 4, 256, 0, stream>>>(offs, csr_src, es,
                                                    (const float4*)M, (float4*)out);
}

// Round 5
// 215.765 us; speedup vs baseline: 2.2034x; 1.3084x over previous
//
#include <hip/hip_runtime.h>
#include <math.h>

#define N_NODES 100000
#define DIM 64
#define N_EDGES 1600000

#define NB 391          // coarse buckets: col >> 8 (ceil(100000/256) = 391)
#define SC_CHUNK 4096   // edges per scatter block
#define SC_BLOCKS ((N_EDGES + SC_CHUNK - 1) / SC_CHUNK)  // 391

#define HB 128          // histogram blocks inside phase1
#define LIN_BLOCKS 1563 // ceil(6250 waves / 4 per block); 16 rows/wave
#define P1_BLOCKS (HB + LIN_BLOCKS)

typedef _Float16 half8 __attribute__((ext_vector_type(8)));
typedef float f32x4 __attribute__((ext_vector_type(4)));

// ---------------------------------------------------------------------------
// Phase 1 (block-specialized):
//   blocks [0, HB): coarse histogram of col>>8 with LDS privatization
//   blocks [HB, ..): MFMA f16 GEMM [16 x 64] @ [64 x 128] per wave
//     C cols 0..63  -> M = x@Wm + bm  (also es = exp(mean_row(M)))
//     C cols 64..127-> out = x@Wr + br
// ---------------------------------------------------------------------------
__global__ __launch_bounds__(256) void k_phase1(
        const float* __restrict__ x,
        const float* __restrict__ Wm, const float* __restrict__ bm,
        const float* __restrict__ Wr, const float* __restrict__ br,
        const int* __restrict__ col, int* __restrict__ hist,
        float* __restrict__ M, float* __restrict__ es, float* __restrict__ out) {
    __shared__ int cnt[NB];
    if (blockIdx.x < HB) {
        for (int i = threadIdx.x; i < NB; i += 256) cnt[i] = 0;
        __syncthreads();
        for (int e = blockIdx.x * 256 + threadIdx.x; e < N_EDGES; e += HB * 256)
            atomicAdd(&cnt[col[e] >> 8], 1);
        __syncthreads();
        for (int i = threadIdx.x; i < NB; i += 256)
            if (cnt[i]) atomicAdd(&hist[i], cnt[i]);
        return;
    }

    const int wave = (blockIdx.x - HB) * 4 + (threadIdx.x >> 6);
    if (wave >= N_NODES / 16) return;
    const int lane = threadIdx.x & 63;
    const int quad = lane >> 4;
    const int l15 = lane & 15;
    const int row0 = wave * 16;

    half8 bfrag[8][2];
#pragma unroll
    for (int ct = 0; ct < 8; ++ct) {
        const float* W = (ct < 4) ? Wm : Wr;
        const int c = (ct & 3) * 16 + l15;
#pragma unroll
        for (int kc = 0; kc < 2; ++kc) {
            half8 f;
#pragma unroll
            for (int j = 0; j < 8; ++j)
                f[j] = (_Float16)W[(kc * 32 + quad * 8 + j) * DIM + c];
            bfrag[ct][kc] = f;
        }
    }

    half8 afrag[2];
#pragma unroll
    for (int kc = 0; kc < 2; ++kc) {
        const float* xp = x + (size_t)(row0 + l15) * DIM + kc * 32 + quad * 8;
        const float4 x0 = *(const float4*)xp;
        const float4 x1 = *(const float4*)(xp + 4);
        half8 f;
        f[0] = (_Float16)x0.x; f[1] = (_Float16)x0.y;
        f[2] = (_Float16)x0.z; f[3] = (_Float16)x0.w;
        f[4] = (_Float16)x1.x; f[5] = (_Float16)x1.y;
        f[6] = (_Float16)x1.z; f[7] = (_Float16)x1.w;
        afrag[kc] = f;
    }

    f32x4 acc[8];
#pragma unroll
    for (int ct = 0; ct < 8; ++ct) {
        f32x4 a = {0.f, 0.f, 0.f, 0.f};
        a = __builtin_amdgcn_mfma_f32_16x16x32_f16(afrag[0], bfrag[ct][0], a, 0, 0, 0);
        a = __builtin_amdgcn_mfma_f32_16x16x32_f16(afrag[1], bfrag[ct][1], a, 0, 0, 0);
        acc[ct] = a;
    }

    float rsum[4] = {0.f, 0.f, 0.f, 0.f};
#pragma unroll
    for (int ct = 0; ct < 8; ++ct) {
        const float bias = (ct < 4) ? bm[(ct & 3) * 16 + l15]
                                    : br[(ct & 3) * 16 + l15];
        float* dst = (ct < 4) ? M : out;
#pragma unroll
        for (int r = 0; r < 4; ++r) {
            const float v = acc[ct][r] + bias;
            dst[(size_t)(row0 + quad * 4 + r) * DIM + (ct & 3) * 16 + l15] = v;
            if (ct < 4) rsum[r] += v;
        }
    }
#pragma unroll
    for (int o = 1; o <= 8; o <<= 1) {
#pragma unroll
        for (int r = 0; r < 4; ++r) rsum[r] += __shfl_xor(rsum[r], o, 64);
    }
    if (l15 == 0) {
#pragma unroll
        for (int r = 0; r < 4; ++r)
            es[row0 + quad * 4 + r] = __expf(rsum[r] * (1.0f / DIM));
    }
}

// ---------------------------------------------------------------------------
// Scan the 391-bin coarse histogram -> bases and working cursors.
// ---------------------------------------------------------------------------
__global__ __launch_bounds__(512) void k_scanB(
        const int* __restrict__ hist, int* __restrict__ bases,
        int* __restrict__ cursor) {
    __shared__ int sd[512];
    const int t = threadIdx.x;
    const int v = (t < NB) ? hist[t] : 0;
    sd[t] = v;
    __syncthreads();
    for (int o = 1; o < 512; o <<= 1) {
        const int add = (t >= o) ? sd[t - o] : 0;
        __syncthreads();
        sd[t] += add;
        __syncthreads();
    }
    if (t < NB) {
        const int base = sd[t] - v;
        bases[t] = base;
        cursor[t] = base;
    }
}

// ---------------------------------------------------------------------------
// Scatter: each block counting-sorts its 4096-edge chunk by coarse bucket in
// LDS, reserves one global range per nonzero bin (aggregated atomic), writes
// packed edges ((row<<8)|(col&255)) bucket-contiguous and coalesced. The
// coarse bucket id of a global slot is implied by its position (bases[]).
// ---------------------------------------------------------------------------
__global__ __launch_bounds__(512) void k_scatter(
        const int* __restrict__ row, const int* __restrict__ col,
        int* __restrict__ cursor, unsigned int* __restrict__ pairs) {
    __shared__ int cnt[NB];
    __shared__ int base_l[NB];
    __shared__ int base_g[NB];
    __shared__ int sd[512];
    __shared__ unsigned int stage[SC_CHUNK];
    __shared__ unsigned short stage_bk[SC_CHUNK];

    const int t = threadIdx.x;
    const int start = blockIdx.x * SC_CHUNK;
    const int mEnd = min(N_EDGES, start + SC_CHUNK);

    for (int i = t; i < NB; i += 512) cnt[i] = 0;
    __syncthreads();

    int rr[8], cc[8], lr[8];
#pragma unroll
    for (int k = 0; k < 8; ++k) {
        const int idx = start + k * 512 + t;
        if (idx < mEnd) {
            cc[k] = col[idx];
            rr[k] = row[idx];
            lr[k] = atomicAdd(&cnt[cc[k] >> 8], 1);
        }
    }
    __syncthreads();

    const int v = (t < NB) ? cnt[t] : 0;
    sd[t] = v;
    __syncthreads();
    for (int o = 1; o < 512; o <<= 1) {
        const int add = (t >= o) ? sd[t - o] : 0;
        __syncthreads();
        sd[t] += add;
        __syncthreads();
    }
    if (t < NB) {
        base_l[t] = sd[t] - v;
        if (v > 0) base_g[t] = atomicAdd(&cursor[t], v);
    }
    __syncthreads();

#pragma unroll
    for (int k = 0; k < 8; ++k) {
        const int idx = start + k * 512 + t;
        if (idx < mEnd) {
            const int bk = cc[k] >> 8;
            const int slot = base_l[bk] + lr[k];
            stage[slot] = ((unsigned int)rr[k] << 8) | (unsigned int)(cc[k] & 255);
            stage_bk[slot] = (unsigned short)bk;
        }
    }
    __syncthreads();

    const int m = mEnd - start;
    for (int i = t; i < m; i += 512) {
        const int bk = stage_bk[i];
        pairs[base_g[bk] + (i - base_l[bk])] = stage[i];
    }
}

// ---------------------------------------------------------------------------
// Per-bucket counting sort: one block per coarse bucket (256 cols). Produces
// offs[] (global CSR offsets) and csr_src[] (source node per edge slot).
// LDS atomics only.
// ---------------------------------------------------------------------------
__global__ __launch_bounds__(256) void k_bucket(
        const unsigned int* __restrict__ pairs, const int* __restrict__ hist,
        const int* __restrict__ bases, int* __restrict__ csr_src,
        int* __restrict__ offs) {
    __shared__ int cnt[256];
    __shared__ int off_l[256];
    const int b = blockIdx.x;
    const int t = threadIdx.x;
    const int base = bases[b];
    const int m = hist[b];

    cnt[t] = 0;
    __syncthreads();
    for (int i = t; i < m; i += 256)
        atomicAdd(&cnt[pairs[base + i] & 255u], 1);
    __syncthreads();

    // exclusive scan of cnt -> off_l
    const int v = cnt[t];
    off_l[t] = v;
    __syncthreads();
    for (int o = 1; o < 256; o <<= 1) {
        const int add = (t >= o) ? off_l[t - o] : 0;
        __syncthreads();
        off_l[t] += add;
        __syncthreads();
    }
    const int excl = off_l[t] - v;

    const int gc = b * 256 + t;
    if (gc < N_NODES) offs[gc] = base + excl;
    if (b == 0 && t == 0) offs[N_NODES] = N_EDGES;

    __syncthreads();
    off_l[t] = excl;
    cnt[t] = 0;
    __syncthreads();

    for (int i = t; i < m; i += 256) {
        const unsigned int p = pairs[base + i];
        const int c = (int)(p & 255u);
        const int r = atomicAdd(&cnt[c], 1);
        csr_src[base + off_l[c] + r] = (int)(p >> 8);
    }
}

// ---------------------------------------------------------------------------
// Gather: one wave per node; 4 groups of 16 lanes; 2 independent edge chains
// per group. float4 M loads.
// ---------------------------------------------------------------------------
__global__ __launch_bounds__(256) void k_gather(
        const int* __restrict__ offs, const int* __restrict__ csr_src,
        const float* __restrict__ es, const float4* __restrict__ M4,
        float4* __restrict__ out4) {
    const int lane = threadIdx.x & 63;
    const int gl = lane & 15;
    const int g  = lane >> 4;
    const int n = (blockIdx.x * blockDim.x + threadIdx.x) >> 6;
    if (n >= N_NODES) return;
    const int beg = offs[n], end = offs[n + 1];
    if (beg == end) return;  // out stays x@Wr + br

    float a0x = 0.f, a0y = 0.f, a0z = 0.f, a0w = 0.f, l0 = 0.f;
    float a1x = 0.f, a1y = 0.f, a1z = 0.f, a1w = 0.f, l1 = 0.f;
    int i = beg + g;
    for (; i + 4 < end; i += 8) {
        const int s0 = csr_src[i];
        const int s1 = csr_src[i + 4];
        const float w0 = es[s0];
        const float w1 = es[s1];
        const float4 m0 = M4[(size_t)s0 * 16 + gl];
        const float4 m1 = M4[(size_t)s1 * 16 + gl];
        l0 += w0; l1 += w1;
        a0x = fmaf(w0, m0.x, a0x); a0y = fmaf(w0, m0.y, a0y);
        a0z = fmaf(w0, m0.z, a0z); a0w = fmaf(w0, m0.w, a0w);
        a1x = fmaf(w1, m1.x, a1x); a1y = fmaf(w1, m1.y, a1y);
        a1z = fmaf(w1, m1.z, a1z); a1w = fmaf(w1, m1.w, a1w);
    }
    if (i < end) {
        const int s0 = csr_src[i];
        const float w0 = es[s0];
        const float4 m0 = M4[(size_t)s0 * 16 + gl];
        l0 += w0;
        a0x = fmaf(w0, m0.x, a0x); a0y = fmaf(w0, m0.y, a0y);
        a0z = fmaf(w0, m0.z, a0z); a0w = fmaf(w0, m0.w, a0w);
    }
    float ax = a0x + a1x, ay = a0y + a1y, az = a0z + a1z, aw = a0w + a1w;
    float l = l0 + l1;
#pragma unroll
    for (int o = 16; o <= 32; o <<= 1) {
        ax += __shfl_xor(ax, o, 64);
        ay += __shfl_xor(ay, o, 64);
        az += __shfl_xor(az, o, 64);
        aw += __shfl_xor(aw, o, 64);
        l  += __shfl_xor(l,  o, 64);
    }
    if (g == 0) {
        const float inv = 1.0f / l;
        float4 r = out4[(size_t)n * 16 + gl];
        r.x = fmaf(ax, inv, r.x);
        r.y = fmaf(ay, inv, r.y);
        r.z = fmaf(az, inv, r.z);
        r.w = fmaf(aw, inv, r.w);
        out4[(size_t)n * 16 + gl] = r;
    }
}

// ---------------------------------------------------------------------------
extern "C" void kernel_launch(void* const* d_in, const int* in_sizes, int n_in,
                              void* d_out, int out_size, void* d_ws, size_t ws_size,
                              hipStream_t stream) {
    const float* x  = (const float*)d_in[0];
    const int*   ei = (const int*)d_in[1];
    const float* Wm = (const float*)d_in[2];
    const float* bm = (const float*)d_in[3];
    const float* Wr = (const float*)d_in[4];
    const float* br = (const float*)d_in[5];
    float* out = (float*)d_out;
    const int* row = ei;            // edge_index[0]
    const int* col = ei + N_EDGES;  // edge_index[1]

    char* ws = (char*)d_ws;
    float* M        = (float*)ws;        ws += (size_t)N_NODES * DIM * sizeof(float);
    float* es       = (float*)ws;        ws += (size_t)N_NODES * sizeof(float);
    int* offs       = (int*)ws;          ws += (size_t)(N_NODES + 1) * sizeof(int);
    int* hist       = (int*)ws;          ws += (size_t)512 * sizeof(int);
    int* bases      = (int*)ws;          ws += (size_t)512 * sizeof(int);
    int* cursor     = (int*)ws;          ws += (size_t)512 * sizeof(int);
    unsigned int* pairs = (unsigned int*)ws; ws += (size_t)N_EDGES * sizeof(unsigned int);
    int* csr_src    = (int*)ws;          ws += (size_t)N_EDGES * sizeof(int);

    hipMemsetAsync(hist, 0, NB * sizeof(int), stream);

    k_phase1<<<P1_BLOCKS, 256, 0, stream>>>(x, Wm, bm, Wr, br,
                                            col, hist, M, es, out);
    k_scanB<<<1, 512, 0, stream>>>(hist, bases, cursor);
    k_scatter<<<SC_BLOCKS, 512, 0, stream>>>(row, col, cursor, pairs);
    k_bucket<<<NB, 256, 0, stream>>>(pairs, hist, bases, csr_src, offs);
    k_gather<<<(N_NODES + 3) / 4, 256, 0, stream>>>(offs, csr_src, es,
                                                    (const float4*)M, (float4*)out);
}

// Round 6
// 195.839 us; speedup vs baseline: 2.4276x; 1.1018x over previous
//
#include <hip/hip_runtime.h>
#include <math.h>

#define N_NODES 100000
#define DIM 64
#define N_EDGES 1600000

#define NB 391          // coarse buckets: col >> 8 (ceil(100000/256) = 391)
#define SC_CHUNK 4096   // edges per scatter block
#define SC_BLOCKS ((N_EDGES + SC_CHUNK - 1) / SC_CHUNK)  // 391

#define HB 128          // histogram blocks inside phase1
#define LIN_BLOCKS 1563 // ceil(6250 waves / 4 per block); 16 rows/wave
#define P1_BLOCKS (HB + LIN_BLOCKS)

typedef _Float16 half8 __attribute__((ext_vector_type(8)));
typedef _Float16 half4 __attribute__((ext_vector_type(4)));
typedef float f32x4 __attribute__((ext_vector_type(4)));

// ---------------------------------------------------------------------------
// Phase 1 (block-specialized):
//   blocks [0, HB): coarse histogram of col>>8 with LDS privatization
//   blocks [HB, ..): MFMA f16 GEMM [16 x 64] @ [64 x 128] per wave
//     C cols 0..63  -> M (stored f16) = x@Wm + bm  (also es = exp(mean_row(M)))
//     C cols 64..127-> out (f32) = x@Wr + br
// ---------------------------------------------------------------------------
__global__ __launch_bounds__(256) void k_phase1(
        const float* __restrict__ x,
        const float* __restrict__ Wm, const float* __restrict__ bm,
        const float* __restrict__ Wr, const float* __restrict__ br,
        const int* __restrict__ col, int* __restrict__ hist,
        _Float16* __restrict__ Mh, float* __restrict__ es,
        float* __restrict__ out) {
    __shared__ int cnt[NB];
    if (blockIdx.x < HB) {
        for (int i = threadIdx.x; i < NB; i += 256) cnt[i] = 0;
        __syncthreads();
        for (int e = blockIdx.x * 256 + threadIdx.x; e < N_EDGES; e += HB * 256)
            atomicAdd(&cnt[col[e] >> 8], 1);
        __syncthreads();
        for (int i = threadIdx.x; i < NB; i += 256)
            if (cnt[i]) atomicAdd(&hist[i], cnt[i]);
        return;
    }

    const int wave = (blockIdx.x - HB) * 4 + (threadIdx.x >> 6);
    if (wave >= N_NODES / 16) return;
    const int lane = threadIdx.x & 63;
    const int quad = lane >> 4;
    const int l15 = lane & 15;
    const int row0 = wave * 16;

    half8 bfrag[8][2];
#pragma unroll
    for (int ct = 0; ct < 8; ++ct) {
        const float* W = (ct < 4) ? Wm : Wr;
        const int c = (ct & 3) * 16 + l15;
#pragma unroll
        for (int kc = 0; kc < 2; ++kc) {
            half8 f;
#pragma unroll
            for (int j = 0; j < 8; ++j)
                f[j] = (_Float16)W[(kc * 32 + quad * 8 + j) * DIM + c];
            bfrag[ct][kc] = f;
        }
    }

    half8 afrag[2];
#pragma unroll
    for (int kc = 0; kc < 2; ++kc) {
        const float* xp = x + (size_t)(row0 + l15) * DIM + kc * 32 + quad * 8;
        const float4 x0 = *(const float4*)xp;
        const float4 x1 = *(const float4*)(xp + 4);
        half8 f;
        f[0] = (_Float16)x0.x; f[1] = (_Float16)x0.y;
        f[2] = (_Float16)x0.z; f[3] = (_Float16)x0.w;
        f[4] = (_Float16)x1.x; f[5] = (_Float16)x1.y;
        f[6] = (_Float16)x1.z; f[7] = (_Float16)x1.w;
        afrag[kc] = f;
    }

    f32x4 acc[8];
#pragma unroll
    for (int ct = 0; ct < 8; ++ct) {
        f32x4 a = {0.f, 0.f, 0.f, 0.f};
        a = __builtin_amdgcn_mfma_f32_16x16x32_f16(afrag[0], bfrag[ct][0], a, 0, 0, 0);
        a = __builtin_amdgcn_mfma_f32_16x16x32_f16(afrag[1], bfrag[ct][1], a, 0, 0, 0);
        acc[ct] = a;
    }

    float rsum[4] = {0.f, 0.f, 0.f, 0.f};
#pragma unroll
    for (int ct = 0; ct < 8; ++ct) {
        const float bias = (ct < 4) ? bm[(ct & 3) * 16 + l15]
                                    : br[(ct & 3) * 16 + l15];
#pragma unroll
        for (int r = 0; r < 4; ++r) {
            const float v = acc[ct][r] + bias;
            const size_t idx = (size_t)(row0 + quad * 4 + r) * DIM + (ct & 3) * 16 + l15;
            if (ct < 4) {
                Mh[idx] = (_Float16)v;
                rsum[r] += v;
            } else {
                out[idx] = v;
            }
        }
    }
#pragma unroll
    for (int o = 1; o <= 8; o <<= 1) {
#pragma unroll
        for (int r = 0; r < 4; ++r) rsum[r] += __shfl_xor(rsum[r], o, 64);
    }
    if (l15 == 0) {
#pragma unroll
        for (int r = 0; r < 4; ++r)
            es[row0 + quad * 4 + r] = __expf(rsum[r] * (1.0f / DIM));
    }
}

// ---------------------------------------------------------------------------
// Scan the 391-bin coarse histogram -> bases and working cursors.
// ---------------------------------------------------------------------------
__global__ __launch_bounds__(512) void k_scanB(
        const int* __restrict__ hist, int* __restrict__ bases,
        int* __restrict__ cursor) {
    __shared__ int sd[512];
    const int t = threadIdx.x;
    const int v = (t < NB) ? hist[t] : 0;
    sd[t] = v;
    __syncthreads();
    for (int o = 1; o < 512; o <<= 1) {
        const int add = (t >= o) ? sd[t - o] : 0;
        __syncthreads();
        sd[t] += add;
        __syncthreads();
    }
    if (t < NB) {
        const int base = sd[t] - v;
        bases[t] = base;
        cursor[t] = base;
    }
}

// ---------------------------------------------------------------------------
// Scatter: each block counting-sorts its 4096-edge chunk by coarse bucket in
// LDS, reserves one global range per nonzero bin (aggregated atomic), writes
// packed edges ((row<<8)|(col&255)) bucket-contiguous and coalesced.
// ---------------------------------------------------------------------------
__global__ __launch_bounds__(512) void k_scatter(
        const int* __restrict__ row, const int* __restrict__ col,
        int* __restrict__ cursor, unsigned int* __restrict__ pairs) {
    __shared__ int cnt[NB];
    __shared__ int base_l[NB];
    __shared__ int base_g[NB];
    __shared__ int sd[512];
    __shared__ unsigned int stage[SC_CHUNK];
    __shared__ unsigned short stage_bk[SC_CHUNK];

    const int t = threadIdx.x;
    const int start = blockIdx.x * SC_CHUNK;
    const int mEnd = min(N_EDGES, start + SC_CHUNK);

    for (int i = t; i < NB; i += 512) cnt[i] = 0;
    __syncthreads();

    int rr[8], cc[8], lr[8];
#pragma unroll
    for (int k = 0; k < 8; ++k) {
        const int idx = start + k * 512 + t;
        if (idx < mEnd) {
            cc[k] = col[idx];
            rr[k] = row[idx];
            lr[k] = atomicAdd(&cnt[cc[k] >> 8], 1);
        }
    }
    __syncthreads();

    const int v = (t < NB) ? cnt[t] : 0;
    sd[t] = v;
    __syncthreads();
    for (int o = 1; o < 512; o <<= 1) {
        const int add = (t >= o) ? sd[t - o] : 0;
        __syncthreads();
        sd[t] += add;
        __syncthreads();
    }
    if (t < NB) {
        base_l[t] = sd[t] - v;
        if (v > 0) base_g[t] = atomicAdd(&cursor[t], v);
    }
    __syncthreads();

#pragma unroll
    for (int k = 0; k < 8; ++k) {
        const int idx = start + k * 512 + t;
        if (idx < mEnd) {
            const int bk = cc[k] >> 8;
            const int slot = base_l[bk] + lr[k];
            stage[slot] = ((unsigned int)rr[k] << 8) | (unsigned int)(cc[k] & 255);
            stage_bk[slot] = (unsigned short)bk;
        }
    }
    __syncthreads();

    const int m = mEnd - start;
    for (int i = t; i < m; i += 512) {
        const int bk = stage_bk[i];
        pairs[base_g[bk] + (i - base_l[bk])] = stage[i];
    }
}

// ---------------------------------------------------------------------------
// Per-bucket counting sort: one 1024-thread block per coarse bucket (256
// cols). Produces offs[] and csr_src[]. LDS atomics only. 1024 threads for
// TLP; scan portions guarded to t<256 with uniform barriers.
// ---------------------------------------------------------------------------
__global__ __launch_bounds__(1024) void k_bucket(
        const unsigned int* __restrict__ pairs, const int* __restrict__ hist,
        const int* __restrict__ bases, int* __restrict__ csr_src,
        int* __restrict__ offs) {
    __shared__ int cnt[256];
    __shared__ int off_l[256];
    const int b = blockIdx.x;
    const int t = threadIdx.x;
    const int base = bases[b];
    const int m = hist[b];

    if (t < 256) cnt[t] = 0;
    __syncthreads();
    for (int i = t; i < m; i += 1024)
        atomicAdd(&cnt[pairs[base + i] & 255u], 1);
    __syncthreads();

    int v = 0;
    if (t < 256) {
        v = cnt[t];
        off_l[t] = v;
    }
    __syncthreads();
    for (int o = 1; o < 256; o <<= 1) {
        int add = 0;
        if (t < 256 && t >= o) add = off_l[t - o];
        __syncthreads();
        if (t < 256) off_l[t] += add;
        __syncthreads();
    }
    if (t < 256) {
        const int excl = off_l[t] - v;
        const int gc = b * 256 + t;
        if (gc < N_NODES) offs[gc] = base + excl;
    }
    if (b == 0 && t == 0) offs[N_NODES] = N_EDGES;
    __syncthreads();
    if (t < 256) {
        off_l[t] -= v;  // exclusive
        cnt[t] = 0;
    }
    __syncthreads();

    for (int i = t; i < m; i += 1024) {
        const unsigned int p = pairs[base + i];
        const int c = (int)(p & 255u);
        const int r = atomicAdd(&cnt[c], 1);
        csr_src[base + off_l[c] + r] = (int)(p >> 8);
    }
}

// ---------------------------------------------------------------------------
// Gather: one wave per node; 4 groups of 16 lanes; 2 independent edge chains
// per group. M in f16: 16 lanes x 8B = one 128B line per edge.
// ---------------------------------------------------------------------------
__global__ __launch_bounds__(256) void k_gather(
        const int* __restrict__ offs, const int* __restrict__ csr_src,
        const float* __restrict__ es, const half4* __restrict__ Mh4,
        float4* __restrict__ out4) {
    const int lane = threadIdx.x & 63;
    const int gl = lane & 15;
    const int g  = lane >> 4;
    const int n = (blockIdx.x * blockDim.x + threadIdx.x) >> 6;
    if (n >= N_NODES) return;
    const int beg = offs[n], end = offs[n + 1];
    if (beg == end) return;  // out stays x@Wr + br

    float a0x = 0.f, a0y = 0.f, a0z = 0.f, a0w = 0.f, l0 = 0.f;
    float a1x = 0.f, a1y = 0.f, a1z = 0.f, a1w = 0.f, l1 = 0.f;
    int i = beg + g;
    for (; i + 4 < end; i += 8) {
        const int s0 = csr_src[i];
        const int s1 = csr_src[i + 4];
        const float w0 = es[s0];
        const float w1 = es[s1];
        const half4 m0 = Mh4[(size_t)s0 * 16 + gl];
        const half4 m1 = Mh4[(size_t)s1 * 16 + gl];
        l0 += w0; l1 += w1;
        a0x = fmaf(w0, (float)m0[0], a0x); a0y = fmaf(w0, (float)m0[1], a0y);
        a0z = fmaf(w0, (float)m0[2], a0z); a0w = fmaf(w0, (float)m0[3], a0w);
        a1x = fmaf(w1, (float)m1[0], a1x); a1y = fmaf(w1, (float)m1[1], a1y);
        a1z = fmaf(w1, (float)m1[2], a1z); a1w = fmaf(w1, (float)m1[3], a1w);
    }
    if (i < end) {
        const int s0 = csr_src[i];
        const float w0 = es[s0];
        const half4 m0 = Mh4[(size_t)s0 * 16 + gl];
        l0 += w0;
        a0x = fmaf(w0, (float)m0[0], a0x); a0y = fmaf(w0, (float)m0[1], a0y);
        a0z = fmaf(w0, (float)m0[2], a0z); a0w = fmaf(w0, (float)m0[3], a0w);
    }
    float ax = a0x + a1x, ay = a0y + a1y, az = a0z + a1z, aw = a0w + a1w;
    float l = l0 + l1;
#pragma unroll
    for (int o = 16; o <= 32; o <<= 1) {
        ax += __shfl_xor(ax, o, 64);
        ay += __shfl_xor(ay, o, 64);
        az += __shfl_xor(az, o, 64);
        aw += __shfl_xor(aw, o, 64);
        l  += __shfl_xor(l,  o, 64);
    }
    if (g == 0) {
        const float inv = 1.0f / l;
        float4 r = out4[(size_t)n * 16 + gl];
        r.x = fmaf(ax, inv, r.x);
        r.y = fmaf(ay, inv, r.y);
        r.z = fmaf(az, inv, r.z);
        r.w = fmaf(aw, inv, r.w);
        out4[(size_t)n * 16 + gl] = r;
    }
}

// ---------------------------------------------------------------------------
extern "C" void kernel_launch(void* const* d_in, const int* in_sizes, int n_in,
                              void* d_out, int out_size, void* d_ws, size_t ws_size,
                              hipStream_t stream) {
    const float* x  = (const float*)d_in[0];
    const int*   ei = (const int*)d_in[1];
    const float* Wm = (const float*)d_in[2];
    const float* bm = (const float*)d_in[3];
    const float* Wr = (const float*)d_in[4];
    const float* br = (const float*)d_in[5];
    float* out = (float*)d_out;
    const int* row = ei;            // edge_index[0]
    const int* col = ei + N_EDGES;  // edge_index[1]

    char* ws = (char*)d_ws;
    _Float16* Mh    = (_Float16*)ws;     ws += (size_t)N_NODES * DIM * sizeof(_Float16);
    float* es       = (float*)ws;        ws += (size_t)N_NODES * sizeof(float);
    int* offs       = (int*)ws;          ws += (size_t)(N_NODES + 1) * sizeof(int);
    int* hist       = (int*)ws;          ws += (size_t)512 * sizeof(int);
    int* bases      = (int*)ws;          ws += (size_t)512 * sizeof(int);
    int* cursor     = (int*)ws;          ws += (size_t)512 * sizeof(int);
    unsigned int* pairs = (unsigned int*)ws; ws += (size_t)N_EDGES * sizeof(unsigned int);
    int* csr_src    = (int*)ws;          ws += (size_t)N_EDGES * sizeof(int);

    hipMemsetAsync(hist, 0, NB * sizeof(int), stream);

    k_phase1<<<P1_BLOCKS, 256, 0, stream>>>(x, Wm, bm, Wr, br,
                                            col, hist, Mh, es, out);
    k_scanB<<<1, 512, 0, stream>>>(hist, bases, cursor);
    k_scatter<<<SC_BLOCKS, 512, 0, stream>>>(row, col, cursor, pairs);
    k_bucket<<<NB, 1024, 0, stream>>>(pairs, hist, bases, csr_src, offs);
    k_gather<<<(N_NODES + 3) / 4, 256, 0, stream>>>(offs, csr_src, es,
                                                    (const half4*)Mh, (float4*)out);
}